// Round 10
// baseline (191.001 us; speedup 1.0000x reference)
//
#include <hip/hip_runtime.h>
#include <stdint.h>

#define N_PTS 4096
#define B_SZ 4
#define D_MODEL 256
#define K_NB 16

__device__ __forceinline__ uint64_t shfl_xor_u64(uint64_t v, int m) {
    const uint32_t lo = (uint32_t)__shfl_xor((int)(uint32_t)v, m, 64);
    const uint32_t hi = (uint32_t)__shfl_xor((int)(v >> 32), m, 64);
    return ((uint64_t)hi << 32) | lo;
}

__device__ __forceinline__ uint64_t shfl_up1_u64(uint64_t v) {
    const uint32_t lo = (uint32_t)__shfl_up((int)(uint32_t)v, 1, 64);
    const uint32_t hi = (uint32_t)__shfl_up((int)(v >> 32), 1, 64);
    return ((uint64_t)hi << 32) | lo;
}

// Monotone unsigned image of IEEE f32 bits (total order, negatives first).
// Self-distance can round to a tiny NEGATIVE; this keeps it at rank 0.
__device__ __forceinline__ uint32_t f32_mono(uint32_t u) {
    return (u & 0x80000000u) ? ~u : (u | 0x80000000u);
}
__device__ __forceinline__ float mono_to_f32(uint32_t m) {
    const uint32_t u = (m & 0x80000000u) ? (m ^ 0x80000000u) : ~m;
    return __uint_as_float(u);
}

// VERBATIM R6 structure (passed, 119 us). ONE change: fp contract(off)
// pragma pinning the no-FMA f32 distance arithmetic at codegen level.
// Root cause of R7/R8/R9 failures: HIP's __fmul_rn/__fadd_rn are NOT
// contraction barriers (they lower to plain mul/add), and the default
// -ffp-contract=fast-honor-pragmas let the backend fuse parts of the d2
// chain into v_fma_f32 depending on surrounding code structure — flipping
// a borderline 16th/17th neighbor (the recurring 0.564 absmax). The
// pragma (honored under fast-honor-pragmas) forbids contraction in this
// function, making the oracle-matching no-FMA DAG context-independent.
__global__ __launch_bounds__(256) void knn_attn_kernel(
    const float* __restrict__ xyz, const float* __restrict__ feat,
    float* __restrict__ out)
{
#pragma clang fp contract(off)
    const int lane = threadIdx.x & 63;
    const int q = (int)((blockIdx.x * blockDim.x + threadIdx.x) >> 6);
    const int b = q >> 12;            // N_PTS = 4096
    const int n = q & (N_PTS - 1);

    const float* xb = xyz + (size_t)b * N_PTS * 3;

    // Oracle-exact f32 arithmetic (NO FMA anywhere):
    //   sq  = fl(fl(x2+y2)+z2); dot = fl(fl(fl(xx')+fl(yy'))+fl(zz'))
    //   d2  = fl( fl(sq_n+sq_c) - fl(2*dot) )
    const float xn = xb[3 * n + 0];
    const float yn = xb[3 * n + 1];
    const float zn = xb[3 * n + 2];
    const float sqn = __fadd_rn(__fadd_rn(__fmul_rn(xn, xn), __fmul_rn(yn, yn)),
                                __fmul_rn(zn, zn));

    uint64_t held;
    {   // Chunk 0: 64 keys, cross-lane bitonic sort -> distributed sorted list
        const float cx = xb[3 * lane + 0];
        const float cy = xb[3 * lane + 1];
        const float cz = xb[3 * lane + 2];
        const float sqc = __fadd_rn(
            __fadd_rn(__fmul_rn(cx, cx), __fmul_rn(cy, cy)), __fmul_rn(cz, cz));
        const float dt = __fadd_rn(
            __fadd_rn(__fmul_rn(cx, xn), __fmul_rn(cy, yn)), __fmul_rn(cz, zn));
        const float d2 = __fsub_rn(__fadd_rn(sqn, sqc), __fmul_rn(2.0f, dt));
        uint64_t key = ((uint64_t)f32_mono(__float_as_uint(d2)) << 32)
                       | (uint32_t)lane;
#pragma unroll
        for (int k = 2; k <= 64; k <<= 1) {
#pragma unroll
            for (int j2 = k >> 1; j2 > 0; j2 >>= 1) {
                const uint64_t o = shfl_xor_u64(key, j2);
                const bool keepMin = (((lane & j2) == 0) == ((lane & k) == 0));
                key = ((o < key) == keepMin) ? o : key;
            }
        }
        held = key;  // lane i = rank-i key (ascending)
    }
    float thr_f = mono_to_f32(
        (uint32_t)__builtin_amdgcn_readlane((int)(held >> 32), 16));

    for (int s = 1; s < N_PTS / 64; ++s) {
        const int j = s * 64 + lane;
        const float cx = xb[3 * j + 0];
        const float cy = xb[3 * j + 1];
        const float cz = xb[3 * j + 2];
        const float sqc = __fadd_rn(
            __fadd_rn(__fmul_rn(cx, cx), __fmul_rn(cy, cy)), __fmul_rn(cz, cz));
        const float dt = __fadd_rn(
            __fadd_rn(__fmul_rn(cx, xn), __fmul_rn(cy, yn)), __fmul_rn(cz, zn));
        const float d2 = __fsub_rn(__fadd_rn(sqn, sqc), __fmul_rn(2.0f, dt));

        // Stale-threshold filter (superset of needed inserts — safe: thr_f
        // is monotone non-increasing; inserting a key worse than the
        // current lane-16 key provably leaves lanes 0..16 unchanged).
        uint64_t pass = __ballot(d2 <= thr_f);
        if (pass) {
            const uint32_t d2u = __float_as_uint(d2);
            do {
                const int L = (int)__ffsll((unsigned long long)pass) - 1;
                pass &= pass - 1;
                const uint32_t ru =
                    (uint32_t)__builtin_amdgcn_readlane((int)d2u, L);
                const uint64_t K = ((uint64_t)f32_mono(ru) << 32)
                                   | (uint32_t)(s * 64 + L);
                uint64_t prev = shfl_up1_u64(held);
                prev = (lane == 0) ? 0ull : prev;  // -inf below lane 0
                held = (held <= K) ? held : ((prev <= K) ? K : prev);
            } while (pass);
            thr_f = mono_to_f32(
                (uint32_t)__builtin_amdgcn_readlane((int)(held >> 32), 16));
        }
    }

    // Lane r (r=1..16) holds the rank-r neighbor's index (rank 0 = self).
    const int myidx = (int)(uint32_t)held;

    // ---- Fused attention: lane owns dims [lane*4, lane*4+4) of D=256 ----
    const float* fb = feat + (size_t)b * N_PTS * D_MODEL;
    const float4 qf = *(const float4*)(fb + (size_t)n * D_MODEL + lane * 4);

    float4 vf[K_NB];
    float sc[K_NB];
#pragma unroll
    for (int k = 0; k < K_NB; ++k) {
        const int nbr = __shfl(myidx, k + 1, 64);
        vf[k] = *(const float4*)(fb + (size_t)nbr * D_MODEL + lane * 4);
        float p = qf.x * vf[k].x + qf.y * vf[k].y + qf.z * vf[k].z + qf.w * vf[k].w;
#pragma unroll
        for (int o = 1; o < 64; o <<= 1) p += __shfl_xor(p, o, 64);
        sc[k] = p * 0.0625f;  // SCALE = 1/sqrt(256)
    }

    float mx = sc[0];
#pragma unroll
    for (int k = 1; k < K_NB; ++k) mx = fmaxf(mx, sc[k]);
    float se = 0.0f;
#pragma unroll
    for (int k = 0; k < K_NB; ++k) {
        sc[k] = __expf(sc[k] - mx);
        se += sc[k];
    }
    const float inv = 1.0f / se;

    float4 acc = make_float4(0.f, 0.f, 0.f, 0.f);
#pragma unroll
    for (int k = 0; k < K_NB; ++k) {
        const float w = sc[k] * inv;
        acc.x += w * vf[k].x;
        acc.y += w * vf[k].y;
        acc.z += w * vf[k].z;
        acc.w += w * vf[k].w;
    }
    *(float4*)(out + (size_t)q * D_MODEL + lane * 4) = acc;
}

extern "C" void kernel_launch(void* const* d_in, const int* in_sizes, int n_in,
                              void* d_out, int out_size, void* d_ws, size_t ws_size,
                              hipStream_t stream) {
    const float* xyz  = (const float*)d_in[0];   // (4, 4096, 3) fp32
    const float* feat = (const float*)d_in[1];   // (4, 4096, 256) fp32
    float* out = (float*)d_out;                  // (4, 4096, 256) fp32

    const int n_queries = B_SZ * N_PTS;          // 16384, one wave each
    const int threads = 256;                     // 4 waves/block
    const int blocks = n_queries * 64 / threads; // 4096
    knn_attn_kernel<<<blocks, threads, 0, stream>>>(xyz, feat, out);
}